// Round 19
// baseline (69.084 us; speedup 1.0000x reference)
//
#include <hip/hip_runtime.h>

#define N_NODES 50000
#define N_EDGES 800000
#define N_GRAPHS 64
#define H 64
#define BN 64                                    // nodes per bucket
#define NB ((N_NODES + BN - 1) / BN)             // 782
#define NGRP 8                                   // cursor replicas (XCD groups)
#define CAPG 224                                 // records per (bucket, group)
#define BSTRIDE (NGRP * CAPG)                    // 1792 records per bucket
#define CHUNK 2048
#define BINTHREADS 1024
#define EPT (CHUNK / BINTHREADS)                 // 2 edges per thread
#define NCHUNK ((N_EDGES + CHUNK - 1) / CHUNK)   // 391
#define FTHREADS 512                             // k_fused threads (8 waves)

// ws layout (float units)
#define VALS_OFF  0                              // float2[NB*BSTRIDE] = 11.2 MB
#define ABC_OFF   (NB * BSTRIDE * 2)             // float[3*H]
#define ZERO_OFF  (ABC_OFF + 3 * H)              // zero-region start
#define GSUM_OFF  (ZERO_OFF)                     // float[64]
#define GCNT_OFF  (GSUM_OFF + N_GRAPHS)          // float[64]
#define BCUR_OFF  (GCNT_OFF + N_GRAPHS)          // int[NGRP*NB] (packed)
#define ZERO_BYTES ((2 * N_GRAPHS + NGRP * NB) * 4)

// ---------------------------------------------------------------------------
// k_bin: block-staged scatter (R16 — proven best). Record carries packed
// (src<<6 | dst_local) + exact ea; x[src] gather lives in k_fused.
// Block 0 also folds the encoder+message weights into A/B/C.
__global__ __launch_bounds__(BINTHREADS) void k_bin(
    const float* __restrict__ ea,
    const int* __restrict__ ei, int* __restrict__ bcur,
    float2* __restrict__ vals, float* __restrict__ abc,
    const float* __restrict__ Wn, const float* __restrict__ bn,
    const float* __restrict__ We, const float* __restrict__ be,
    const float* __restrict__ Wm, const float* __restrict__ bm)
{
    __shared__ int lh[NB], lbase[NB], lcur[NB];
    const int t = threadIdx.x;
    const int g = blockIdx.x & (NGRP - 1);
    for (int b = t; b < NB; b += BINTHREADS) { lh[b] = 0; lcur[b] = 0; }

    const int e0 = blockIdx.x * CHUNK;
    const int* __restrict__ src = ei;
    const int* __restrict__ dst = ei + N_EDGES;

    int   s[EPT], d[EPT];
    float ev[EPT];
    bool  ok[EPT];
    #pragma unroll
    for (int k = 0; k < EPT; ++k) {
        const int e = e0 + t + k * BINTHREADS;
        ok[k] = (e < N_EDGES);
        const int ee = ok[k] ? e : (N_EDGES - 1);
        s[k]  = src[ee];
        d[k]  = dst[ee];
        ev[k] = ea[ee];
    }
    __syncthreads();

    #pragma unroll
    for (int k = 0; k < EPT; ++k)
        if (ok[k]) atomicAdd(&lh[d[k] >> 6], 1);
    __syncthreads();

    for (int b = t; b < NB; b += BINTHREADS) {
        const int v = lh[b];
        if (v) lbase[b] = atomicAdd(&bcur[g * NB + b], v);
    }
    __syncthreads();

    #pragma unroll
    for (int k = 0; k < EPT; ++k) {
        if (ok[k]) {
            const int b  = d[k] >> 6;
            const int lp = atomicAdd(&lcur[b], 1);
            const int p  = lbase[b] + lp;
            if (p < CAPG) {
                const int pk = (s[k] << 6) | (d[k] & (BN - 1));
                vals[b * BSTRIDE + g * CAPG + p] =
                    make_float2(__int_as_float(pk), ev[k]);
            }
        }
    }

    // fold A/B/C (consumed by the NEXT kernel — stream order makes this safe)
    if (blockIdx.x == 0 && t < H) {
        const int k = t;
        float a = 0.f, b = 0.f, c = 0.f;
        #pragma unroll
        for (int i = 0; i < H; ++i) {
            float wt = Wm[i * H + k];
            float wb = Wm[(H + i) * H + k];
            a = fmaf(Wn[i], wt, a);
            b = fmaf(We[i], wb, b);
            c = fmaf(bn[i], wt, c);
            c = fmaf(be[i], wb, c);
        }
        abc[k]         = a;
        abc[H + k]     = b;
        abc[2 * H + k] = c + bm[k];
    }
}

// ---------------------------------------------------------------------------
// k_fused: 512 threads / 8 waves — halves the per-wave serial AGG+matvec
// path vs the 4-wave version (all blocks co-resident, so kernel duration
// tracks the per-block critical path). 8 nodes per wave in 2 batches of 4.
__global__ __launch_bounds__(FTHREADS) void k_fused(
    const float2* __restrict__ vals, const int* __restrict__ bcur,
    const float* __restrict__ x,
    const float* __restrict__ abc, const float* __restrict__ Wu,
    const float* __restrict__ bu, const float* __restrict__ Wo,
    const int* __restrict__ batch,
    float* __restrict__ gsum, float* __restrict__ gcnt)
{
    __shared__ float2 stB[BSTRIDE];             // node-sorted (x, ea) (14.3 KB)
    __shared__ int lh[BN], le[BN], lc[BN];
    __shared__ __align__(16) float sA[8][4][68]; // per-wave 4 aggregate rows
    __shared__ float lsum[N_GRAPHS], lcnt[N_GRAPHS];

    const int t    = threadIdx.x;
    const int lane = t & 63;
    const int w    = t >> 6;
    const int b    = blockIdx.x;
    const int base = b * BSTRIDE;

    const float A   = abc[lane];
    const float B   = abc[H + lane];
    const float C   = abc[2 * H + lane];
    const float bul = bu[lane];
    const float wol = Wo[lane];
    float wr[64];
    #pragma unroll
    for (int i = 0; i < 64; ++i) wr[i] = Wu[i * H + lane];

    if (t < BN) lh[t] = 0;
    if (t < N_GRAPHS) { lsum[t] = 0.f; lcnt[t] = 0.f; }
    __syncthreads();

    // group sub-run lengths (uniform scalar loads)
    int mg[NGRP];
    #pragma unroll
    for (int g = 0; g < NGRP; ++g) {
        const int v = bcur[g * NB + b];
        mg[g] = v < CAPG ? v : CAPG;
    }

    // records to registers (coalesced), then independent x gathers, then hist
    float2 r[NGRP];
    #pragma unroll
    for (int g = 0; g < NGRP; ++g)
        if (t < mg[g]) r[g] = vals[base + g * CAPG + t];
    float xv[NGRP];
    int   dl[NGRP];
    #pragma unroll
    for (int g = 0; g < NGRP; ++g) {
        if (t < mg[g]) {
            const int pk = __float_as_int(r[g].x);
            dl[g] = pk & (BN - 1);
            xv[g] = x[pk >> 6];
        }
    }
    #pragma unroll
    for (int g = 0; g < NGRP; ++g)
        if (t < mg[g]) atomicAdd(&lh[dl[g]], 1);
    __syncthreads();

    // exclusive scan of 64 bins (wave 0, shuffle scan)
    if (t < BN) {
        const int v = lh[t];
        int incl = v;
        #pragma unroll
        for (int d = 1; d < BN; d <<= 1) {
            const int up = __shfl_up(incl, d);
            if (lane >= d) incl += up;
        }
        le[t] = incl - v;
        lc[t] = incl - v;
    }
    __syncthreads();

    // regs -> node-sorted LDS with x resolved
    #pragma unroll
    for (int g = 0; g < NGRP; ++g) {
        if (t < mg[g]) {
            const int rk = atomicAdd(&lc[dl[g]], 1);
            stB[rk] = make_float2(xv[g], r[g].y);
        }
    }
    __syncthreads();

    #define MSG(q) fmaxf(fmaf((q).x, A, fmaf((q).y, B, C)), 0.f)
    #define AGG(LN, OUT) { \
        const int off_ = le[LN]; const int c_ = lh[LN]; \
        float s0 = 0.f, s1 = 0.f, s2 = 0.f, s3 = 0.f; \
        int j = 0; \
        for (; j + 8 <= c_; j += 8) { \
            const float2 q0 = stB[off_ + j + 0], q1 = stB[off_ + j + 1]; \
            const float2 q2 = stB[off_ + j + 2], q3 = stB[off_ + j + 3]; \
            const float2 q4 = stB[off_ + j + 4], q5 = stB[off_ + j + 5]; \
            const float2 q6 = stB[off_ + j + 6], q7 = stB[off_ + j + 7]; \
            s0 += MSG(q0); s1 += MSG(q1); s2 += MSG(q2); s3 += MSG(q3); \
            s0 += MSG(q4); s1 += MSG(q5); s2 += MSG(q6); s3 += MSG(q7); \
        } \
        for (; j < c_; ++j) { const float2 q = stB[off_ + j]; s0 += MSG(q); } \
        OUT = (s0 + s1) + (s2 + s3); }

    // per-wave: 8 nodes = 2 batches of 4 (cross-node ILP)
    for (int q = 0; q < 2; ++q) {
        const int ln0 = w * 8 + q * 4;
        float sb0, sb1, sb2, sb3;
        AGG(ln0 + 0, sb0);
        AGG(ln0 + 1, sb1);
        AGG(ln0 + 2, sb2);
        AGG(ln0 + 3, sb3);
        sA[w][0][lane] = sb0;
        sA[w][1][lane] = sb1;
        sA[w][2][lane] = sb2;
        sA[w][3][lane] = sb3;
        // wave-private rows: no barrier needed (compiler inserts lgkmcnt)

        float p0 = 0.f, p1 = 0.f, p2 = 0.f, p3 = 0.f;
        float q0 = 0.f, q1 = 0.f, q2 = 0.f, q3 = 0.f;
        #pragma unroll
        for (int i = 0; i < 64; i += 4) {
            const float4 r0 = *(const float4*)&sA[w][0][i];
            const float4 r1 = *(const float4*)&sA[w][1][i];
            const float4 r2 = *(const float4*)&sA[w][2][i];
            const float4 r3 = *(const float4*)&sA[w][3][i];
            p0 = fmaf(r0.x, wr[i + 0], p0); q0 = fmaf(r0.y, wr[i + 1], q0);
            p0 = fmaf(r0.z, wr[i + 2], p0); q0 = fmaf(r0.w, wr[i + 3], q0);
            p1 = fmaf(r1.x, wr[i + 0], p1); q1 = fmaf(r1.y, wr[i + 1], q1);
            p1 = fmaf(r1.z, wr[i + 2], p1); q1 = fmaf(r1.w, wr[i + 3], q1);
            p2 = fmaf(r2.x, wr[i + 0], p2); q2 = fmaf(r2.y, wr[i + 1], q2);
            p2 = fmaf(r2.z, wr[i + 2], p2); q2 = fmaf(r2.w, wr[i + 3], q2);
            p3 = fmaf(r3.x, wr[i + 0], p3); q3 = fmaf(r3.y, wr[i + 1], q3);
            p3 = fmaf(r3.z, wr[i + 2], p3); q3 = fmaf(r3.w, wr[i + 3], q3);
        }
        float u0 = fmaxf(p0 + q0 + bul, 0.f) * wol;
        float u1 = fmaxf(p1 + q1 + bul, 0.f) * wol;
        float u2 = fmaxf(p2 + q2 + bul, 0.f) * wol;
        float u3 = fmaxf(p3 + q3 + bul, 0.f) * wol;
        #pragma unroll
        for (int off2 = 32; off2 > 0; off2 >>= 1) {
            u0 += __shfl_xor(u0, off2);
            u1 += __shfl_xor(u1, off2);
            u2 += __shfl_xor(u2, off2);
            u3 += __shfl_xor(u3, off2);
        }
        if (lane == 0) {
            const int node0 = b * BN + ln0;
            if (node0 + 0 < N_NODES) { atomicAdd(&lsum[batch[node0 + 0]], u0); atomicAdd(&lcnt[batch[node0 + 0]], 1.f); }
            if (node0 + 1 < N_NODES) { atomicAdd(&lsum[batch[node0 + 1]], u1); atomicAdd(&lcnt[batch[node0 + 1]], 1.f); }
            if (node0 + 2 < N_NODES) { atomicAdd(&lsum[batch[node0 + 2]], u2); atomicAdd(&lcnt[batch[node0 + 2]], 1.f); }
            if (node0 + 3 < N_NODES) { atomicAdd(&lsum[batch[node0 + 3]], u3); atomicAdd(&lcnt[batch[node0 + 3]], 1.f); }
        }
    }
    #undef AGG
    #undef MSG
    __syncthreads();
    if (t < N_GRAPHS && lcnt[t] != 0.f) {
        atomicAdd(&gsum[t], lsum[t]);
        atomicAdd(&gcnt[t], lcnt[t]);
    }
}

// ---------------------------------------------------------------------------
__global__ void k_final(const float* __restrict__ gsum,
                        const float* __restrict__ gcnt,
                        const float* __restrict__ bo,
                        float* __restrict__ out)
{
    const int g = threadIdx.x;
    if (g < N_GRAPHS)
        out[g] = gsum[g] / fmaxf(gcnt[g], 1.f) + bo[0];
}

// ---------------------------------------------------------------------------
extern "C" void kernel_launch(void* const* d_in, const int* in_sizes, int n_in,
                              void* d_out, int out_size, void* d_ws, size_t ws_size,
                              hipStream_t stream)
{
    const float* x      = (const float*)d_in[0];
    const float* ea     = (const float*)d_in[1];
    const int*   ei     = (const int*)  d_in[2];
    const int*   batch  = (const int*)  d_in[3];
    const float* Wn     = (const float*)d_in[4];
    const float* bn     = (const float*)d_in[5];
    const float* We     = (const float*)d_in[6];
    const float* be     = (const float*)d_in[7];
    const float* Wm     = (const float*)d_in[8];
    const float* bm     = (const float*)d_in[9];
    const float* Wu     = (const float*)d_in[10];
    const float* bu     = (const float*)d_in[11];
    const float* Wo     = (const float*)d_in[12];
    const float* bo     = (const float*)d_in[13];

    float*  ws   = (float*)d_ws;
    float2* vals = (float2*)(ws + VALS_OFF);
    float*  abc  = ws + ABC_OFF;
    float*  gsum = ws + GSUM_OFF;
    float*  gcnt = ws + GCNT_OFF;
    int*    bcur = (int*)(ws + BCUR_OFF);
    float*  out  = (float*)d_out;

    hipMemsetAsync(ws + ZERO_OFF, 0, ZERO_BYTES, stream);
    k_bin<<<NCHUNK, BINTHREADS, 0, stream>>>(ea, ei, bcur, vals, abc,
                                             Wn, bn, We, be, Wm, bm);
    k_fused<<<NB, FTHREADS, 0, stream>>>(vals, bcur, x, abc, Wu, bu, Wo, batch,
                                         gsum, gcnt);
    k_final<<<1, 64, 0, stream>>>(gsum, gcnt, bo, out);
}

// Round 20
// 54.042 us; speedup vs baseline: 1.2783x; 1.2783x over previous
//
#include <hip/hip_runtime.h>

#define N_NODES 50000
#define N_EDGES 800000
#define N_GRAPHS 64
#define H 64
#define BN 64                                    // nodes per bucket
#define NB ((N_NODES + BN - 1) / BN)             // 782
#define NGRP 8                                   // cursor replicas (XCD groups)
#define CAPG 224                                 // records per (bucket, group)
#define BSTRIDE (NGRP * CAPG)                    // 1792 records per bucket
#define CHUNK 1024
#define BINTHREADS 512
#define EPT (CHUNK / BINTHREADS)                 // 2 edges per thread
#define NCHUNK ((N_EDGES + CHUNK - 1) / CHUNK)   // 782 -> 3.05 blocks/CU (balance)

// ws layout (float units)
#define VALS_OFF  0                              // float2[NB*BSTRIDE] = 11.2 MB
#define ABC_OFF   (NB * BSTRIDE * 2)             // float[3*H]
#define ZERO_OFF  (ABC_OFF + 3 * H)              // zero-region start
#define GSUM_OFF  (ZERO_OFF)                     // float[64]
#define GCNT_OFF  (GSUM_OFF + N_GRAPHS)          // float[64]
#define BCUR_OFF  (GCNT_OFF + N_GRAPHS)          // int[NGRP*NB] (packed)
#define ZERO_BYTES ((2 * N_GRAPHS + NGRP * NB) * 4)

// ---------------------------------------------------------------------------
// k_bin: block-staged scatter (R16 structure; 512-thread blocks for even
// CU distribution — 782 blocks = 3.05/CU vs 391 = 1.53/CU tail imbalance).
// Record carries packed (src<<6 | dst_local) + exact ea; x[src] gather
// lives in k_fused. Block 0 also folds A/B/C.
__global__ __launch_bounds__(BINTHREADS) void k_bin(
    const float* __restrict__ ea,
    const int* __restrict__ ei, int* __restrict__ bcur,
    float2* __restrict__ vals, float* __restrict__ abc,
    const float* __restrict__ Wn, const float* __restrict__ bn,
    const float* __restrict__ We, const float* __restrict__ be,
    const float* __restrict__ Wm, const float* __restrict__ bm)
{
    __shared__ int lh[NB], lbase[NB], lcur[NB];
    const int t = threadIdx.x;
    const int g = blockIdx.x & (NGRP - 1);
    for (int b = t; b < NB; b += BINTHREADS) { lh[b] = 0; lcur[b] = 0; }

    const int e0 = blockIdx.x * CHUNK;
    const int* __restrict__ src = ei;
    const int* __restrict__ dst = ei + N_EDGES;

    int   s[EPT], d[EPT];
    float ev[EPT];
    bool  ok[EPT];
    #pragma unroll
    for (int k = 0; k < EPT; ++k) {
        const int e = e0 + t + k * BINTHREADS;
        ok[k] = (e < N_EDGES);
        const int ee = ok[k] ? e : (N_EDGES - 1);
        s[k]  = src[ee];
        d[k]  = dst[ee];
        ev[k] = ea[ee];
    }
    __syncthreads();

    #pragma unroll
    for (int k = 0; k < EPT; ++k)
        if (ok[k]) atomicAdd(&lh[d[k] >> 6], 1);
    __syncthreads();

    for (int b = t; b < NB; b += BINTHREADS) {
        const int v = lh[b];
        if (v) lbase[b] = atomicAdd(&bcur[g * NB + b], v);
    }
    __syncthreads();

    #pragma unroll
    for (int k = 0; k < EPT; ++k) {
        if (ok[k]) {
            const int b  = d[k] >> 6;
            const int lp = atomicAdd(&lcur[b], 1);
            const int p  = lbase[b] + lp;
            if (p < CAPG) {
                const int pk = (s[k] << 6) | (d[k] & (BN - 1));
                vals[b * BSTRIDE + g * CAPG + p] =
                    make_float2(__int_as_float(pk), ev[k]);
            }
        }
    }

    // fold A/B/C (consumed by the NEXT kernel — stream order makes this safe)
    if (blockIdx.x == 0 && t < H) {
        const int k = t;
        float a = 0.f, b = 0.f, c = 0.f;
        #pragma unroll
        for (int i = 0; i < H; ++i) {
            float wt = Wm[i * H + k];
            float wb = Wm[(H + i) * H + k];
            a = fmaf(Wn[i], wt, a);
            b = fmaf(We[i], wb, b);
            c = fmaf(bn[i], wt, c);
            c = fmaf(be[i], wb, c);
        }
        abc[k]         = a;
        abc[H + k]     = b;
        abc[2 * H + k] = c + bm[k];
    }
}

// ---------------------------------------------------------------------------
// k_fused (R16 form — 256 threads, 4 waves, 16 nodes/wave; both wider
// variants measured slower): load 8 group sub-runs to registers, gather
// x[src] (L2-resident, hidden), LDS histogram, wave-0 shuffle scan, regs ->
// node-sorted LDS, per-wave 16 nodes in 4 batches of 4 (cross-node ILP),
// pool into LDS graph bins -> global atomics.
__global__ __launch_bounds__(256) void k_fused(
    const float2* __restrict__ vals, const int* __restrict__ bcur,
    const float* __restrict__ x,
    const float* __restrict__ abc, const float* __restrict__ Wu,
    const float* __restrict__ bu, const float* __restrict__ Wo,
    const int* __restrict__ batch,
    float* __restrict__ gsum, float* __restrict__ gcnt)
{
    __shared__ float2 stB[BSTRIDE];             // node-sorted (x, ea) (14.3 KB)
    __shared__ int lh[BN], le[BN], lc[BN];
    __shared__ __align__(16) float sA[4][4][68]; // per-wave 4 aggregate rows
    __shared__ float lsum[N_GRAPHS], lcnt[N_GRAPHS];

    const int t    = threadIdx.x;
    const int lane = t & 63;
    const int w    = t >> 6;
    const int b    = blockIdx.x;
    const int base = b * BSTRIDE;

    const float A   = abc[lane];
    const float B   = abc[H + lane];
    const float C   = abc[2 * H + lane];
    const float bul = bu[lane];
    const float wol = Wo[lane];
    float wr[64];
    #pragma unroll
    for (int i = 0; i < 64; ++i) wr[i] = Wu[i * H + lane];

    if (t < BN) lh[t] = 0;
    if (t < N_GRAPHS) { lsum[t] = 0.f; lcnt[t] = 0.f; }
    __syncthreads();

    // group sub-run lengths (uniform scalar loads)
    int mg[NGRP];
    #pragma unroll
    for (int g = 0; g < NGRP; ++g) {
        const int v = bcur[g * NB + b];
        mg[g] = v < CAPG ? v : CAPG;
    }

    // records to registers (coalesced), then independent x gathers, then hist
    float2 r[NGRP];
    #pragma unroll
    for (int g = 0; g < NGRP; ++g)
        if (t < mg[g]) r[g] = vals[base + g * CAPG + t];
    float xv[NGRP];
    int   dl[NGRP];
    #pragma unroll
    for (int g = 0; g < NGRP; ++g) {
        if (t < mg[g]) {
            const int pk = __float_as_int(r[g].x);
            dl[g] = pk & (BN - 1);
            xv[g] = x[pk >> 6];
        }
    }
    #pragma unroll
    for (int g = 0; g < NGRP; ++g)
        if (t < mg[g]) atomicAdd(&lh[dl[g]], 1);
    __syncthreads();

    // exclusive scan of 64 bins (wave 0, shuffle scan)
    if (t < BN) {
        const int v = lh[t];
        int incl = v;
        #pragma unroll
        for (int d = 1; d < BN; d <<= 1) {
            const int up = __shfl_up(incl, d);
            if (lane >= d) incl += up;
        }
        le[t] = incl - v;
        lc[t] = incl - v;
    }
    __syncthreads();

    // regs -> node-sorted LDS with x resolved
    #pragma unroll
    for (int g = 0; g < NGRP; ++g) {
        if (t < mg[g]) {
            const int rk = atomicAdd(&lc[dl[g]], 1);
            stB[rk] = make_float2(xv[g], r[g].y);
        }
    }
    __syncthreads();

    #define MSG(q) fmaxf(fmaf((q).x, A, fmaf((q).y, B, C)), 0.f)
    #define AGG(LN, OUT) { \
        const int off_ = le[LN]; const int c_ = lh[LN]; \
        float s0 = 0.f, s1 = 0.f, s2 = 0.f, s3 = 0.f; \
        int j = 0; \
        for (; j + 8 <= c_; j += 8) { \
            const float2 q0 = stB[off_ + j + 0], q1 = stB[off_ + j + 1]; \
            const float2 q2 = stB[off_ + j + 2], q3 = stB[off_ + j + 3]; \
            const float2 q4 = stB[off_ + j + 4], q5 = stB[off_ + j + 5]; \
            const float2 q6 = stB[off_ + j + 6], q7 = stB[off_ + j + 7]; \
            s0 += MSG(q0); s1 += MSG(q1); s2 += MSG(q2); s3 += MSG(q3); \
            s0 += MSG(q4); s1 += MSG(q5); s2 += MSG(q6); s3 += MSG(q7); \
        } \
        for (; j < c_; ++j) { const float2 q = stB[off_ + j]; s0 += MSG(q); } \
        OUT = (s0 + s1) + (s2 + s3); }

    // per-wave: 16 nodes = 4 batches of 4 (cross-node ILP)
    for (int q = 0; q < 4; ++q) {
        const int ln0 = w * 16 + q * 4;
        float sb0, sb1, sb2, sb3;
        AGG(ln0 + 0, sb0);
        AGG(ln0 + 1, sb1);
        AGG(ln0 + 2, sb2);
        AGG(ln0 + 3, sb3);
        sA[w][0][lane] = sb0;
        sA[w][1][lane] = sb1;
        sA[w][2][lane] = sb2;
        sA[w][3][lane] = sb3;
        // wave-private rows: no barrier needed (compiler inserts lgkmcnt)

        float p0 = 0.f, p1 = 0.f, p2 = 0.f, p3 = 0.f;
        float q0 = 0.f, q1 = 0.f, q2 = 0.f, q3 = 0.f;
        #pragma unroll
        for (int i = 0; i < 64; i += 4) {
            const float4 r0 = *(const float4*)&sA[w][0][i];
            const float4 r1 = *(const float4*)&sA[w][1][i];
            const float4 r2 = *(const float4*)&sA[w][2][i];
            const float4 r3 = *(const float4*)&sA[w][3][i];
            p0 = fmaf(r0.x, wr[i + 0], p0); q0 = fmaf(r0.y, wr[i + 1], q0);
            p0 = fmaf(r0.z, wr[i + 2], p0); q0 = fmaf(r0.w, wr[i + 3], q0);
            p1 = fmaf(r1.x, wr[i + 0], p1); q1 = fmaf(r1.y, wr[i + 1], q1);
            p1 = fmaf(r1.z, wr[i + 2], p1); q1 = fmaf(r1.w, wr[i + 3], q1);
            p2 = fmaf(r2.x, wr[i + 0], p2); q2 = fmaf(r2.y, wr[i + 1], q2);
            p2 = fmaf(r2.z, wr[i + 2], p2); q2 = fmaf(r2.w, wr[i + 3], q2);
            p3 = fmaf(r3.x, wr[i + 0], p3); q3 = fmaf(r3.y, wr[i + 1], q3);
            p3 = fmaf(r3.z, wr[i + 2], p3); q3 = fmaf(r3.w, wr[i + 3], q3);
        }
        float u0 = fmaxf(p0 + q0 + bul, 0.f) * wol;
        float u1 = fmaxf(p1 + q1 + bul, 0.f) * wol;
        float u2 = fmaxf(p2 + q2 + bul, 0.f) * wol;
        float u3 = fmaxf(p3 + q3 + bul, 0.f) * wol;
        #pragma unroll
        for (int off2 = 32; off2 > 0; off2 >>= 1) {
            u0 += __shfl_xor(u0, off2);
            u1 += __shfl_xor(u1, off2);
            u2 += __shfl_xor(u2, off2);
            u3 += __shfl_xor(u3, off2);
        }
        if (lane == 0) {
            const int node0 = b * BN + ln0;
            if (node0 + 0 < N_NODES) { atomicAdd(&lsum[batch[node0 + 0]], u0); atomicAdd(&lcnt[batch[node0 + 0]], 1.f); }
            if (node0 + 1 < N_NODES) { atomicAdd(&lsum[batch[node0 + 1]], u1); atomicAdd(&lcnt[batch[node0 + 1]], 1.f); }
            if (node0 + 2 < N_NODES) { atomicAdd(&lsum[batch[node0 + 2]], u2); atomicAdd(&lcnt[batch[node0 + 2]], 1.f); }
            if (node0 + 3 < N_NODES) { atomicAdd(&lsum[batch[node0 + 3]], u3); atomicAdd(&lcnt[batch[node0 + 3]], 1.f); }
        }
    }
    #undef AGG
    #undef MSG
    __syncthreads();
    if (t < N_GRAPHS && lcnt[t] != 0.f) {
        atomicAdd(&gsum[t], lsum[t]);
        atomicAdd(&gcnt[t], lcnt[t]);
    }
}

// ---------------------------------------------------------------------------
__global__ void k_final(const float* __restrict__ gsum,
                        const float* __restrict__ gcnt,
                        const float* __restrict__ bo,
                        float* __restrict__ out)
{
    const int g = threadIdx.x;
    if (g < N_GRAPHS)
        out[g] = gsum[g] / fmaxf(gcnt[g], 1.f) + bo[0];
}

// ---------------------------------------------------------------------------
extern "C" void kernel_launch(void* const* d_in, const int* in_sizes, int n_in,
                              void* d_out, int out_size, void* d_ws, size_t ws_size,
                              hipStream_t stream)
{
    const float* x      = (const float*)d_in[0];
    const float* ea     = (const float*)d_in[1];
    const int*   ei     = (const int*)  d_in[2];
    const int*   batch  = (const int*)  d_in[3];
    const float* Wn     = (const float*)d_in[4];
    const float* bn     = (const float*)d_in[5];
    const float* We     = (const float*)d_in[6];
    const float* be     = (const float*)d_in[7];
    const float* Wm     = (const float*)d_in[8];
    const float* bm     = (const float*)d_in[9];
    const float* Wu     = (const float*)d_in[10];
    const float* bu     = (const float*)d_in[11];
    const float* Wo     = (const float*)d_in[12];
    const float* bo     = (const float*)d_in[13];

    float*  ws   = (float*)d_ws;
    float2* vals = (float2*)(ws + VALS_OFF);
    float*  abc  = ws + ABC_OFF;
    float*  gsum = ws + GSUM_OFF;
    float*  gcnt = ws + GCNT_OFF;
    int*    bcur = (int*)(ws + BCUR_OFF);
    float*  out  = (float*)d_out;

    hipMemsetAsync(ws + ZERO_OFF, 0, ZERO_BYTES, stream);
    k_bin<<<NCHUNK, BINTHREADS, 0, stream>>>(ea, ei, bcur, vals, abc,
                                             Wn, bn, We, be, Wm, bm);
    k_fused<<<NB, 256, 0, stream>>>(vals, bcur, x, abc, Wu, bu, Wo, batch,
                                    gsum, gcnt);
    k_final<<<1, 64, 0, stream>>>(gsum, gcnt, bo, out);
}

// Round 21
// 51.126 us; speedup vs baseline: 1.3513x; 1.0570x over previous
//
#include <hip/hip_runtime.h>

#define N_NODES 50000
#define N_EDGES 800000
#define N_GRAPHS 64
#define H 64
#define BN 64                                    // nodes per bucket
#define NB ((N_NODES + BN - 1) / BN)             // 782
#define NGRP 8                                   // cursor replicas (XCD groups)
#define CAPG 224                                 // records per (bucket, group)
#define BSTRIDE (NGRP * CAPG)                    // 1792 records per bucket
#define CHUNK 2048
#define BINTHREADS 1024
#define EPT (CHUNK / BINTHREADS)                 // 2 edges per thread
#define NCHUNK ((N_EDGES + CHUNK - 1) / CHUNK)   // 391

// ws layout (float units)
#define VALS_OFF  0                              // float2[NB*BSTRIDE] = 11.2 MB
#define ABC_OFF   (NB * BSTRIDE * 2)             // float[3*H]
#define ZERO_OFF  (ABC_OFF + 3 * H)              // zero-region start
#define GSUM_OFF  (ZERO_OFF)                     // float[64]
#define GCNT_OFF  (GSUM_OFF + N_GRAPHS)          // float[64]
#define BCUR_OFF  (GCNT_OFF + N_GRAPHS)          // int[NGRP*NB] (packed)
#define ZERO_BYTES ((2 * N_GRAPHS + NGRP * NB) * 4)

// ---------------------------------------------------------------------------
// k_bin: block-staged scatter (R16 — measured optimum of this design space).
// Record carries packed (src<<6 | dst_local) + exact ea; x[src] gather lives
// in k_fused (keeps the only high-latency dependent load off this kernel's
// critical path). Block 0 also folds the encoder+message weights into A/B/C.
// Measured-dead alternatives: direct per-edge tickets (R15, write-amp 2.4x),
// cursor line-padding (R17, +7.7us), 4B records (R18, random-gather FETCH
// explosion), 512-thr blocks (R20, +2.9us).
__global__ __launch_bounds__(BINTHREADS) void k_bin(
    const float* __restrict__ ea,
    const int* __restrict__ ei, int* __restrict__ bcur,
    float2* __restrict__ vals, float* __restrict__ abc,
    const float* __restrict__ Wn, const float* __restrict__ bn,
    const float* __restrict__ We, const float* __restrict__ be,
    const float* __restrict__ Wm, const float* __restrict__ bm)
{
    __shared__ int lh[NB], lbase[NB], lcur[NB];
    const int t = threadIdx.x;
    const int g = blockIdx.x & (NGRP - 1);
    for (int b = t; b < NB; b += BINTHREADS) { lh[b] = 0; lcur[b] = 0; }

    const int e0 = blockIdx.x * CHUNK;
    const int* __restrict__ src = ei;
    const int* __restrict__ dst = ei + N_EDGES;

    int   s[EPT], d[EPT];
    float ev[EPT];
    bool  ok[EPT];
    #pragma unroll
    for (int k = 0; k < EPT; ++k) {
        const int e = e0 + t + k * BINTHREADS;
        ok[k] = (e < N_EDGES);
        const int ee = ok[k] ? e : (N_EDGES - 1);
        s[k]  = src[ee];
        d[k]  = dst[ee];
        ev[k] = ea[ee];
    }
    __syncthreads();

    #pragma unroll
    for (int k = 0; k < EPT; ++k)
        if (ok[k]) atomicAdd(&lh[d[k] >> 6], 1);
    __syncthreads();

    for (int b = t; b < NB; b += BINTHREADS) {
        const int v = lh[b];
        if (v) lbase[b] = atomicAdd(&bcur[g * NB + b], v);
    }
    __syncthreads();

    #pragma unroll
    for (int k = 0; k < EPT; ++k) {
        if (ok[k]) {
            const int b  = d[k] >> 6;
            const int lp = atomicAdd(&lcur[b], 1);
            const int p  = lbase[b] + lp;
            if (p < CAPG) {
                const int pk = (s[k] << 6) | (d[k] & (BN - 1));
                vals[b * BSTRIDE + g * CAPG + p] =
                    make_float2(__int_as_float(pk), ev[k]);
            }
        }
    }

    // fold A/B/C (consumed by the NEXT kernel — stream order makes this safe)
    if (blockIdx.x == 0 && t < H) {
        const int k = t;
        float a = 0.f, b = 0.f, c = 0.f;
        #pragma unroll
        for (int i = 0; i < H; ++i) {
            float wt = Wm[i * H + k];
            float wb = Wm[(H + i) * H + k];
            a = fmaf(Wn[i], wt, a);
            b = fmaf(We[i], wb, b);
            c = fmaf(bn[i], wt, c);
            c = fmaf(be[i], wb, c);
        }
        abc[k]         = a;
        abc[H + k]     = b;
        abc[2 * H + k] = c + bm[k];
    }
}

// ---------------------------------------------------------------------------
// k_fused (R16 form — 256 threads, 4 waves, 16 nodes/wave; 512-thread and
// 8-wave variants both measured slower): load 8 group sub-runs to registers,
// gather x[src] (L2-resident, latency-hidden), LDS histogram, wave-0 shuffle
// scan, regs -> node-sorted LDS, per-wave 16 nodes in 4 batches of 4
// (cross-node ILP), pool into LDS graph bins -> global atomics.
__global__ __launch_bounds__(256) void k_fused(
    const float2* __restrict__ vals, const int* __restrict__ bcur,
    const float* __restrict__ x,
    const float* __restrict__ abc, const float* __restrict__ Wu,
    const float* __restrict__ bu, const float* __restrict__ Wo,
    const int* __restrict__ batch,
    float* __restrict__ gsum, float* __restrict__ gcnt)
{
    __shared__ float2 stB[BSTRIDE];             // node-sorted (x, ea) (14.3 KB)
    __shared__ int lh[BN], le[BN], lc[BN];
    __shared__ __align__(16) float sA[4][4][68]; // per-wave 4 aggregate rows
    __shared__ float lsum[N_GRAPHS], lcnt[N_GRAPHS];

    const int t    = threadIdx.x;
    const int lane = t & 63;
    const int w    = t >> 6;
    const int b    = blockIdx.x;
    const int base = b * BSTRIDE;

    const float A   = abc[lane];
    const float B   = abc[H + lane];
    const float C   = abc[2 * H + lane];
    const float bul = bu[lane];
    const float wol = Wo[lane];
    float wr[64];
    #pragma unroll
    for (int i = 0; i < 64; ++i) wr[i] = Wu[i * H + lane];

    if (t < BN) lh[t] = 0;
    if (t < N_GRAPHS) { lsum[t] = 0.f; lcnt[t] = 0.f; }
    __syncthreads();

    // group sub-run lengths (uniform scalar loads)
    int mg[NGRP];
    #pragma unroll
    for (int g = 0; g < NGRP; ++g) {
        const int v = bcur[g * NB + b];
        mg[g] = v < CAPG ? v : CAPG;
    }

    // records to registers (coalesced), then independent x gathers, then hist
    float2 r[NGRP];
    #pragma unroll
    for (int g = 0; g < NGRP; ++g)
        if (t < mg[g]) r[g] = vals[base + g * CAPG + t];
    float xv[NGRP];
    int   dl[NGRP];
    #pragma unroll
    for (int g = 0; g < NGRP; ++g) {
        if (t < mg[g]) {
            const int pk = __float_as_int(r[g].x);
            dl[g] = pk & (BN - 1);
            xv[g] = x[pk >> 6];
        }
    }
    #pragma unroll
    for (int g = 0; g < NGRP; ++g)
        if (t < mg[g]) atomicAdd(&lh[dl[g]], 1);
    __syncthreads();

    // exclusive scan of 64 bins (wave 0, shuffle scan)
    if (t < BN) {
        const int v = lh[t];
        int incl = v;
        #pragma unroll
        for (int d = 1; d < BN; d <<= 1) {
            const int up = __shfl_up(incl, d);
            if (lane >= d) incl += up;
        }
        le[t] = incl - v;
        lc[t] = incl - v;
    }
    __syncthreads();

    // regs -> node-sorted LDS with x resolved
    #pragma unroll
    for (int g = 0; g < NGRP; ++g) {
        if (t < mg[g]) {
            const int rk = atomicAdd(&lc[dl[g]], 1);
            stB[rk] = make_float2(xv[g], r[g].y);
        }
    }
    __syncthreads();

    #define MSG(q) fmaxf(fmaf((q).x, A, fmaf((q).y, B, C)), 0.f)
    #define AGG(LN, OUT) { \
        const int off_ = le[LN]; const int c_ = lh[LN]; \
        float s0 = 0.f, s1 = 0.f, s2 = 0.f, s3 = 0.f; \
        int j = 0; \
        for (; j + 8 <= c_; j += 8) { \
            const float2 q0 = stB[off_ + j + 0], q1 = stB[off_ + j + 1]; \
            const float2 q2 = stB[off_ + j + 2], q3 = stB[off_ + j + 3]; \
            const float2 q4 = stB[off_ + j + 4], q5 = stB[off_ + j + 5]; \
            const float2 q6 = stB[off_ + j + 6], q7 = stB[off_ + j + 7]; \
            s0 += MSG(q0); s1 += MSG(q1); s2 += MSG(q2); s3 += MSG(q3); \
            s0 += MSG(q4); s1 += MSG(q5); s2 += MSG(q6); s3 += MSG(q7); \
        } \
        for (; j < c_; ++j) { const float2 q = stB[off_ + j]; s0 += MSG(q); } \
        OUT = (s0 + s1) + (s2 + s3); }

    // per-wave: 16 nodes = 4 batches of 4 (cross-node ILP)
    for (int q = 0; q < 4; ++q) {
        const int ln0 = w * 16 + q * 4;
        float sb0, sb1, sb2, sb3;
        AGG(ln0 + 0, sb0);
        AGG(ln0 + 1, sb1);
        AGG(ln0 + 2, sb2);
        AGG(ln0 + 3, sb3);
        sA[w][0][lane] = sb0;
        sA[w][1][lane] = sb1;
        sA[w][2][lane] = sb2;
        sA[w][3][lane] = sb3;
        // wave-private rows: no barrier needed (compiler inserts lgkmcnt)

        float p0 = 0.f, p1 = 0.f, p2 = 0.f, p3 = 0.f;
        float q0 = 0.f, q1 = 0.f, q2 = 0.f, q3 = 0.f;
        #pragma unroll
        for (int i = 0; i < 64; i += 4) {
            const float4 r0 = *(const float4*)&sA[w][0][i];
            const float4 r1 = *(const float4*)&sA[w][1][i];
            const float4 r2 = *(const float4*)&sA[w][2][i];
            const float4 r3 = *(const float4*)&sA[w][3][i];
            p0 = fmaf(r0.x, wr[i + 0], p0); q0 = fmaf(r0.y, wr[i + 1], q0);
            p0 = fmaf(r0.z, wr[i + 2], p0); q0 = fmaf(r0.w, wr[i + 3], q0);
            p1 = fmaf(r1.x, wr[i + 0], p1); q1 = fmaf(r1.y, wr[i + 1], q1);
            p1 = fmaf(r1.z, wr[i + 2], p1); q1 = fmaf(r1.w, wr[i + 3], q1);
            p2 = fmaf(r2.x, wr[i + 0], p2); q2 = fmaf(r2.y, wr[i + 1], q2);
            p2 = fmaf(r2.z, wr[i + 2], p2); q2 = fmaf(r2.w, wr[i + 3], q2);
            p3 = fmaf(r3.x, wr[i + 0], p3); q3 = fmaf(r3.y, wr[i + 1], q3);
            p3 = fmaf(r3.z, wr[i + 2], p3); q3 = fmaf(r3.w, wr[i + 3], q3);
        }
        float u0 = fmaxf(p0 + q0 + bul, 0.f) * wol;
        float u1 = fmaxf(p1 + q1 + bul, 0.f) * wol;
        float u2 = fmaxf(p2 + q2 + bul, 0.f) * wol;
        float u3 = fmaxf(p3 + q3 + bul, 0.f) * wol;
        #pragma unroll
        for (int off2 = 32; off2 > 0; off2 >>= 1) {
            u0 += __shfl_xor(u0, off2);
            u1 += __shfl_xor(u1, off2);
            u2 += __shfl_xor(u2, off2);
            u3 += __shfl_xor(u3, off2);
        }
        if (lane == 0) {
            const int node0 = b * BN + ln0;
            if (node0 + 0 < N_NODES) { atomicAdd(&lsum[batch[node0 + 0]], u0); atomicAdd(&lcnt[batch[node0 + 0]], 1.f); }
            if (node0 + 1 < N_NODES) { atomicAdd(&lsum[batch[node0 + 1]], u1); atomicAdd(&lcnt[batch[node0 + 1]], 1.f); }
            if (node0 + 2 < N_NODES) { atomicAdd(&lsum[batch[node0 + 2]], u2); atomicAdd(&lcnt[batch[node0 + 2]], 1.f); }
            if (node0 + 3 < N_NODES) { atomicAdd(&lsum[batch[node0 + 3]], u3); atomicAdd(&lcnt[batch[node0 + 3]], 1.f); }
        }
    }
    #undef AGG
    #undef MSG
    __syncthreads();
    if (t < N_GRAPHS && lcnt[t] != 0.f) {
        atomicAdd(&gsum[t], lsum[t]);
        atomicAdd(&gcnt[t], lcnt[t]);
    }
}

// ---------------------------------------------------------------------------
__global__ void k_final(const float* __restrict__ gsum,
                        const float* __restrict__ gcnt,
                        const float* __restrict__ bo,
                        float* __restrict__ out)
{
    const int g = threadIdx.x;
    if (g < N_GRAPHS)
        out[g] = gsum[g] / fmaxf(gcnt[g], 1.f) + bo[0];
}

// ---------------------------------------------------------------------------
extern "C" void kernel_launch(void* const* d_in, const int* in_sizes, int n_in,
                              void* d_out, int out_size, void* d_ws, size_t ws_size,
                              hipStream_t stream)
{
    const float* x      = (const float*)d_in[0];
    const float* ea     = (const float*)d_in[1];
    const int*   ei     = (const int*)  d_in[2];
    const int*   batch  = (const int*)  d_in[3];
    const float* Wn     = (const float*)d_in[4];
    const float* bn     = (const float*)d_in[5];
    const float* We     = (const float*)d_in[6];
    const float* be     = (const float*)d_in[7];
    const float* Wm     = (const float*)d_in[8];
    const float* bm     = (const float*)d_in[9];
    const float* Wu     = (const float*)d_in[10];
    const float* bu     = (const float*)d_in[11];
    const float* Wo     = (const float*)d_in[12];
    const float* bo     = (const float*)d_in[13];

    float*  ws   = (float*)d_ws;
    float2* vals = (float2*)(ws + VALS_OFF);
    float*  abc  = ws + ABC_OFF;
    float*  gsum = ws + GSUM_OFF;
    float*  gcnt = ws + GCNT_OFF;
    int*    bcur = (int*)(ws + BCUR_OFF);
    float*  out  = (float*)d_out;

    hipMemsetAsync(ws + ZERO_OFF, 0, ZERO_BYTES, stream);
    k_bin<<<NCHUNK, BINTHREADS, 0, stream>>>(ea, ei, bcur, vals, abc,
                                             Wn, bn, We, be, Wm, bm);
    k_fused<<<NB, 256, 0, stream>>>(vals, bcur, x, abc, Wu, bu, Wo, batch,
                                    gsum, gcnt);
    k_final<<<1, 64, 0, stream>>>(gsum, gcnt, bo, out);
}